// Round 4
// baseline (370.857 us; speedup 1.0000x reference)
//
#include <hip/hip_runtime.h>
#include <math.h>

// True clang vector type (nontemporal builtins reject HIP_vector_type structs).
typedef float vfloat4 __attribute__((ext_vector_type(4)));

// ws layout (memset to 0 at launch):
//   double wsd[3]   @0  : ssq_w, ssq_dw, sum_abs
//   uint   cnt[2]   @24 : ticket counters (reduce, consolidate)
//   float  wsf[2]   @32 : final_strength, forgetting_strength
#define RED_UNROLL 8
#define CON_UNROLL 8

__global__ __launch_bounds__(256) void wc_reduce(const vfloat4* __restrict__ w,
                                                 const vfloat4* __restrict__ dw,
                                                 double* __restrict__ wsd,
                                                 unsigned int* __restrict__ cnt,
                                                 float* __restrict__ wsf,
                                                 const float* __restrict__ fg_w1,
                                                 const float* __restrict__ fg_b1,
                                                 const float* __restrict__ fg_w2,
                                                 const float* __restrict__ fg_b2,
                                                 float* __restrict__ out_tail,
                                                 int n4) {
    int tid = blockIdx.x * blockDim.x + threadIdx.x;
    int stride = gridDim.x * blockDim.x;
    float sw0 = 0.f, sw1 = 0.f, sw2 = 0.f, sw3 = 0.f;
    float sd0 = 0.f, sd1 = 0.f, sd2 = 0.f, sd3 = 0.f;
    int i = tid;
    for (; i + (RED_UNROLL - 1) * stride < n4; i += RED_UNROLL * stride) {
        vfloat4 a[RED_UNROLL], b[RED_UNROLL];
#pragma unroll
        for (int u = 0; u < RED_UNROLL; u++) a[u] = w[i + u * stride];
#pragma unroll
        for (int u = 0; u < RED_UNROLL; u++) b[u] = dw[i + u * stride];   // L3-warm: no nt!
#pragma unroll
        for (int u = 0; u < RED_UNROLL; u++) {
            sw0 = fmaf(a[u].x, a[u].x, sw0);
            sw1 = fmaf(a[u].y, a[u].y, sw1);
            sw2 = fmaf(a[u].z, a[u].z, sw2);
            sw3 = fmaf(a[u].w, a[u].w, sw3);
            sd0 = fmaf(b[u].x, b[u].x, sd0);
            sd1 = fmaf(b[u].y, b[u].y, sd1);
            sd2 = fmaf(b[u].z, b[u].z, sd2);
            sd3 = fmaf(b[u].w, b[u].w, sd3);
        }
    }
    for (; i < n4; i += stride) {
        vfloat4 a = w[i];
        vfloat4 b = dw[i];
        sw0 = fmaf(a.x, a.x, sw0); sw1 = fmaf(a.y, a.y, sw1);
        sw2 = fmaf(a.z, a.z, sw2); sw3 = fmaf(a.w, a.w, sw3);
        sd0 = fmaf(b.x, b.x, sd0); sd1 = fmaf(b.y, b.y, sd1);
        sd2 = fmaf(b.z, b.z, sd2); sd3 = fmaf(b.w, b.w, sd3);
    }
    float sw = (sw0 + sw1) + (sw2 + sw3);
    float sdw = (sd0 + sd1) + (sd2 + sd3);
    for (int off = 32; off > 0; off >>= 1) {
        sw  += __shfl_down(sw, off);
        sdw += __shfl_down(sdw, off);
    }
    __shared__ float lsw[4], lsdw[4];
    int wave = threadIdx.x >> 6;
    int lane = threadIdx.x & 63;
    if (lane == 0) { lsw[wave] = sw; lsdw[wave] = sdw; }
    __syncthreads();
    if (threadIdx.x == 0) {
        atomicAdd(&wsd[0], (double)(lsw[0] + lsw[1] + lsw[2] + lsw[3]));
        atomicAdd(&wsd[1], (double)(lsdw[0] + lsdw[1] + lsdw[2] + lsdw[3]));
        __threadfence();
        unsigned int t = atomicAdd(&cnt[0], 1u);
        if (t == gridDim.x - 1) {
            // Last block: all wsd atomics are globally visible. Fused scalar stage.
            double ssw = atomicAdd(&wsd[0], 0.0);   // device-scope coherent read
            double ssd = atomicAdd(&wsd[1], 0.0);
            float normw = sqrtf((float)ssw);
            float fs = 1.0f / (1.0f + expf(-normw));
            fs = fminf(fmaxf(fs, 0.0f), 1.0f);
            float cm = sqrtf((float)ssd);
            const float tf = 0.01f, fr = 0.0001f;
            float acc = fg_b2[0];
            for (int j = 0; j < 8; j++) {
                float h = tf * fg_w1[2 * j + 0] + fr * fg_w1[2 * j + 1] + fg_b1[j];
                acc = fmaf(fmaxf(h, 0.0f), fg_w2[j], acc);
            }
            float fg = 1.0f / (1.0f + expf(-acc));
            wsf[0] = fs;
            wsf[1] = fg;
            out_tail[0] = fs;     // final_strength
            out_tail[1] = cm;     // change_magnitude
            out_tail[2] = fg;     // forgetting_strength
            out_tail[4] = 0.5f;   // weight_stability
            out_tail[5] = 0.0f;   // memory_strength
        }
    }
}

__global__ __launch_bounds__(256) void wc_consolidate(const vfloat4* __restrict__ w,
                                                      vfloat4* __restrict__ outw,
                                                      const float* __restrict__ ur_w1,
                                                      const float* __restrict__ ur_b1,
                                                      const float* __restrict__ ur_w2,
                                                      const float* __restrict__ ur_b2,
                                                      const float* __restrict__ wsf,
                                                      double* __restrict__ wsd,
                                                      unsigned int* __restrict__ cnt,
                                                      float* __restrict__ out_tail,
                                                      float inv_n, int n4) {
    float fs = wsf[0];   // written by wc_reduce's last block; stream-ordered
    float fg = wsf[1];
    float a0[16], hb[16], w2[16];
#pragma unroll
    for (int k = 0; k < 16; k++) {
        a0[k] = ur_w1[3 * k + 0];
        hb[k] = fmaf(fs, ur_w1[3 * k + 1], fmaf(fg, ur_w1[3 * k + 2], ur_b1[k]));
        w2[k] = ur_w2[k];
    }
    float b2 = ur_b2[0];

    int tid = blockIdx.x * blockDim.x + threadIdx.x;
    int stride = gridDim.x * blockDim.x;
    float sabs = 0.f;
    int i = tid;
    for (; i + (CON_UNROLL - 1) * stride < n4; i += CON_UNROLL * stride) {
        vfloat4 v[CON_UNROLL];
#pragma unroll
        for (int u = 0; u < CON_UNROLL; u++) v[u] = w[i + u * stride];
#pragma unroll
        for (int u = 0; u < CON_UNROLL; u++) {
            vfloat4 o;
#pragma unroll
            for (int e = 0; e < 4; e++) {
                float x = v[u][e];
                float acc = b2;
#pragma unroll
                for (int k = 0; k < 16; k++) {
                    float h = fmaf(x, a0[k], hb[k]);
                    acc = fmaf(fmaxf(h, 0.0f), w2[k], acc);
                }
                float t = __expf(2.0f * acc);
                float th = fmaf(-2.0f, __builtin_amdgcn_rcpf(t + 1.0f), 1.0f);
                float nw = fmaf(0.001f, th, x);
                nw = fminf(fmaxf(nw, -10.0f), 10.0f);
                o[e] = nw;
                sabs += fabsf(nw);
            }
            __builtin_nontemporal_store(o, &outw[i + u * stride]);
        }
    }
    for (; i < n4; i += stride) {
        vfloat4 v = w[i];
        vfloat4 o;
#pragma unroll
        for (int e = 0; e < 4; e++) {
            float x = v[e];
            float acc = b2;
#pragma unroll
            for (int k = 0; k < 16; k++) {
                float h = fmaf(x, a0[k], hb[k]);
                acc = fmaf(fmaxf(h, 0.0f), w2[k], acc);
            }
            float t = __expf(2.0f * acc);
            float th = fmaf(-2.0f, __builtin_amdgcn_rcpf(t + 1.0f), 1.0f);
            float nw = fmaf(0.001f, th, x);
            nw = fminf(fmaxf(nw, -10.0f), 10.0f);
            o[e] = nw;
            sabs += fabsf(nw);
        }
        outw[i] = o;
    }
    for (int off = 32; off > 0; off >>= 1) sabs += __shfl_down(sabs, off);
    __shared__ float ls[4];
    int wave = threadIdx.x >> 6;
    int lane = threadIdx.x & 63;
    if (lane == 0) ls[wave] = sabs;
    __syncthreads();
    if (threadIdx.x == 0) {
        atomicAdd(&wsd[2], (double)(ls[0] + ls[1] + ls[2] + ls[3]));
        __threadfence();
        unsigned int t = atomicAdd(&cnt[1], 1u);
        if (t == gridDim.x - 1) {
            // Fused finalize stage.
            double sa = atomicAdd(&wsd[2], 0.0);
            float mean_abs = (float)sa * inv_n;
            float dq = (mean_abs > 0.1f && mean_abs < 0.9f) ? 1.0f : mean_abs;
            out_tail[3] = (0.5f + dq) * 0.5f;  // consolidation_quality
        }
    }
}

extern "C" void kernel_launch(void* const* d_in, const int* in_sizes, int n_in,
                              void* d_out, int out_size, void* d_ws, size_t ws_size,
                              hipStream_t stream) {
    const float* cur_w = (const float*)d_in[0];
    const float* w_chg = (const float*)d_in[1];
    const float* ur_w1 = (const float*)d_in[2];
    const float* ur_b1 = (const float*)d_in[3];
    const float* ur_w2 = (const float*)d_in[4];
    const float* ur_b2 = (const float*)d_in[5];
    const float* fg_w1 = (const float*)d_in[6];
    const float* fg_b1 = (const float*)d_in[7];
    const float* fg_w2 = (const float*)d_in[8];
    const float* fg_b2 = (const float*)d_in[9];

    int n = in_sizes[0];          // 16777216 (4096x4096)
    int n4 = n / 4;

    double* wsd = (double*)d_ws;
    unsigned int* cnt = (unsigned int*)((char*)d_ws + 24);
    float* wsf = (float*)((char*)d_ws + 32);

    float* out_w = (float*)d_out;
    float* out_tail = out_w + n;

    // Zero the 40-byte scratch header (async memset is graph-capturable).
    hipMemsetAsync(d_ws, 0, 40, stream);

    const int threads = 256;
    const int blocks = 2048;   // 2048*256*8(unroll)*4(vec) == 16.7M exactly: no tail iterations

    wc_reduce<<<blocks, threads, 0, stream>>>((const vfloat4*)cur_w, (const vfloat4*)w_chg,
                                              wsd, cnt, wsf, fg_w1, fg_b1, fg_w2, fg_b2,
                                              out_tail, n4);

    wc_consolidate<<<blocks, threads, 0, stream>>>((const vfloat4*)cur_w, (vfloat4*)out_w,
                                                   ur_w1, ur_b1, ur_w2, ur_b2, wsf, wsd, cnt,
                                                   out_tail, 1.0f / (float)n, n4);
}

// Round 5
// 212.145 us; speedup vs baseline: 1.7481x; 1.7481x over previous
//
#include <hip/hip_runtime.h>
#include <math.h>

// True clang vector types (nontemporal builtins reject HIP_vector_type structs).
typedef float vfloat4 __attribute__((ext_vector_type(4)));
typedef float vfloat2 __attribute__((ext_vector_type(2)));

#define RED_UNROLL 8
#define CON_UNROLL 8
#define NBLK 2048

// ws layout (no init needed -- everything read is written first each call):
//   vfloat2 red_part[NBLK] @0      : per-block (ssq_w, ssq_dw) partials
//   float   abs_part[NBLK] @16384  : per-block sum|new_w| partials
//   float   wsf[2]         @24576  : final_strength, forgetting_strength

__global__ __launch_bounds__(256) void wc_reduce(const vfloat4* __restrict__ w,
                                                 const vfloat4* __restrict__ dw,
                                                 vfloat2* __restrict__ red_part,
                                                 int n4) {
    int tid = blockIdx.x * blockDim.x + threadIdx.x;
    int stride = gridDim.x * blockDim.x;
    float sw0 = 0.f, sw1 = 0.f, sw2 = 0.f, sw3 = 0.f;
    float sd0 = 0.f, sd1 = 0.f, sd2 = 0.f, sd3 = 0.f;
    int i = tid;
    for (; i + (RED_UNROLL - 1) * stride < n4; i += RED_UNROLL * stride) {
        vfloat4 a[RED_UNROLL], b[RED_UNROLL];
#pragma unroll
        for (int u = 0; u < RED_UNROLL; u++) a[u] = w[i + u * stride];
#pragma unroll
        for (int u = 0; u < RED_UNROLL; u++) b[u] = __builtin_nontemporal_load(&dw[i + u * stride]);
#pragma unroll
        for (int u = 0; u < RED_UNROLL; u++) {
            sw0 = fmaf(a[u].x, a[u].x, sw0);
            sw1 = fmaf(a[u].y, a[u].y, sw1);
            sw2 = fmaf(a[u].z, a[u].z, sw2);
            sw3 = fmaf(a[u].w, a[u].w, sw3);
            sd0 = fmaf(b[u].x, b[u].x, sd0);
            sd1 = fmaf(b[u].y, b[u].y, sd1);
            sd2 = fmaf(b[u].z, b[u].z, sd2);
            sd3 = fmaf(b[u].w, b[u].w, sd3);
        }
    }
    for (; i < n4; i += stride) {
        vfloat4 a = w[i];
        vfloat4 b = dw[i];
        sw0 = fmaf(a.x, a.x, sw0); sw1 = fmaf(a.y, a.y, sw1);
        sw2 = fmaf(a.z, a.z, sw2); sw3 = fmaf(a.w, a.w, sw3);
        sd0 = fmaf(b.x, b.x, sd0); sd1 = fmaf(b.y, b.y, sd1);
        sd2 = fmaf(b.z, b.z, sd2); sd3 = fmaf(b.w, b.w, sd3);
    }
    float sw = (sw0 + sw1) + (sw2 + sw3);
    float sdw = (sd0 + sd1) + (sd2 + sd3);
    for (int off = 32; off > 0; off >>= 1) {
        sw  += __shfl_down(sw, off);
        sdw += __shfl_down(sdw, off);
    }
    __shared__ float lsw[4], lsdw[4];
    int wave = threadIdx.x >> 6;
    int lane = threadIdx.x & 63;
    if (lane == 0) { lsw[wave] = sw; lsdw[wave] = sdw; }
    __syncthreads();
    if (threadIdx.x == 0) {
        vfloat2 p;
        p.x = (lsw[0] + lsw[1]) + (lsw[2] + lsw[3]);
        p.y = (lsdw[0] + lsdw[1]) + (lsdw[2] + lsdw[3]);
        red_part[blockIdx.x] = p;   // contention-free partial store (no atomics!)
    }
}

// Stage 2: one block reduces the 2048 partials in double and computes scalars.
__global__ __launch_bounds__(1024) void wc_scalars(const vfloat2* __restrict__ red_part,
                                                   float* __restrict__ wsf,
                                                   const float* __restrict__ fg_w1,
                                                   const float* __restrict__ fg_b1,
                                                   const float* __restrict__ fg_w2,
                                                   const float* __restrict__ fg_b2,
                                                   float* __restrict__ out_tail) {
    double sw = 0.0, sdw = 0.0;
    for (int i = threadIdx.x; i < NBLK; i += 1024) {
        vfloat2 p = red_part[i];
        sw += (double)p.x;
        sdw += (double)p.y;
    }
    for (int off = 32; off > 0; off >>= 1) {
        sw  += __shfl_down(sw, off);
        sdw += __shfl_down(sdw, off);
    }
    __shared__ double lsw[16], lsd[16];
    int wave = threadIdx.x >> 6;
    int lane = threadIdx.x & 63;
    if (lane == 0) { lsw[wave] = sw; lsd[wave] = sdw; }
    __syncthreads();
    if (threadIdx.x == 0) {
        double tw = 0.0, td = 0.0;
        for (int k = 0; k < 16; k++) { tw += lsw[k]; td += lsd[k]; }
        float normw = sqrtf((float)tw);
        float fs = 1.0f / (1.0f + expf(-normw));
        fs = fminf(fmaxf(fs, 0.0f), 1.0f);
        float cm = sqrtf((float)td);
        const float tf = 0.01f, fr = 0.0001f;
        float acc = fg_b2[0];
        for (int j = 0; j < 8; j++) {
            float h = tf * fg_w1[2 * j + 0] + fr * fg_w1[2 * j + 1] + fg_b1[j];
            acc = fmaf(fmaxf(h, 0.0f), fg_w2[j], acc);
        }
        float fg = 1.0f / (1.0f + expf(-acc));
        wsf[0] = fs;
        wsf[1] = fg;
        out_tail[0] = fs;     // final_strength
        out_tail[1] = cm;     // change_magnitude
        out_tail[2] = fg;     // forgetting_strength
        out_tail[4] = 0.5f;   // weight_stability
        out_tail[5] = 0.0f;   // memory_strength
    }
}

__global__ __launch_bounds__(256) void wc_consolidate(const vfloat4* __restrict__ w,
                                                      vfloat4* __restrict__ outw,
                                                      const float* __restrict__ ur_w1,
                                                      const float* __restrict__ ur_b1,
                                                      const float* __restrict__ ur_w2,
                                                      const float* __restrict__ ur_b2,
                                                      const float* __restrict__ wsf,
                                                      float* __restrict__ abs_part,
                                                      int n4) {
    float fs = wsf[0];
    float fg = wsf[1];
    float a0[16], hb[16], w2[16];
#pragma unroll
    for (int k = 0; k < 16; k++) {
        a0[k] = ur_w1[3 * k + 0];
        hb[k] = fmaf(fs, ur_w1[3 * k + 1], fmaf(fg, ur_w1[3 * k + 2], ur_b1[k]));
        w2[k] = ur_w2[k];
    }
    float b2 = ur_b2[0];

    int tid = blockIdx.x * blockDim.x + threadIdx.x;
    int stride = gridDim.x * blockDim.x;
    float sabs = 0.f;
    int i = tid;
    for (; i + (CON_UNROLL - 1) * stride < n4; i += CON_UNROLL * stride) {
        vfloat4 v[CON_UNROLL];
#pragma unroll
        for (int u = 0; u < CON_UNROLL; u++) v[u] = w[i + u * stride];
#pragma unroll
        for (int u = 0; u < CON_UNROLL; u++) {
            vfloat4 o;
#pragma unroll
            for (int e = 0; e < 4; e++) {
                float x = v[u][e];
                float acc = b2;
#pragma unroll
                for (int k = 0; k < 16; k++) {
                    float h = fmaf(x, a0[k], hb[k]);
                    acc = fmaf(fmaxf(h, 0.0f), w2[k], acc);
                }
                float t = __expf(2.0f * acc);
                float th = fmaf(-2.0f, __builtin_amdgcn_rcpf(t + 1.0f), 1.0f);
                float nw = fmaf(0.001f, th, x);
                nw = fminf(fmaxf(nw, -10.0f), 10.0f);
                o[e] = nw;
                sabs += fabsf(nw);
            }
            __builtin_nontemporal_store(o, &outw[i + u * stride]);
        }
    }
    for (; i < n4; i += stride) {
        vfloat4 v = w[i];
        vfloat4 o;
#pragma unroll
        for (int e = 0; e < 4; e++) {
            float x = v[e];
            float acc = b2;
#pragma unroll
            for (int k = 0; k < 16; k++) {
                float h = fmaf(x, a0[k], hb[k]);
                acc = fmaf(fmaxf(h, 0.0f), w2[k], acc);
            }
            float t = __expf(2.0f * acc);
            float th = fmaf(-2.0f, __builtin_amdgcn_rcpf(t + 1.0f), 1.0f);
            float nw = fmaf(0.001f, th, x);
            nw = fminf(fmaxf(nw, -10.0f), 10.0f);
            o[e] = nw;
            sabs += fabsf(nw);
        }
        outw[i] = o;
    }
    for (int off = 32; off > 0; off >>= 1) sabs += __shfl_down(sabs, off);
    __shared__ float ls[4];
    int wave = threadIdx.x >> 6;
    int lane = threadIdx.x & 63;
    if (lane == 0) ls[wave] = sabs;
    __syncthreads();
    if (threadIdx.x == 0) {
        abs_part[blockIdx.x] = (ls[0] + ls[1]) + (ls[2] + ls[3]);  // no atomics
    }
}

__global__ __launch_bounds__(1024) void wc_finalize(const float* __restrict__ abs_part,
                                                    float* __restrict__ out_tail,
                                                    double inv_n) {
    double sa = 0.0;
    for (int i = threadIdx.x; i < NBLK; i += 1024) sa += (double)abs_part[i];
    for (int off = 32; off > 0; off >>= 1) sa += __shfl_down(sa, off);
    __shared__ double ls[16];
    int wave = threadIdx.x >> 6;
    int lane = threadIdx.x & 63;
    if (lane == 0) ls[wave] = sa;
    __syncthreads();
    if (threadIdx.x == 0) {
        double t = 0.0;
        for (int k = 0; k < 16; k++) t += ls[k];
        float mean_abs = (float)(t * inv_n);
        float dq = (mean_abs > 0.1f && mean_abs < 0.9f) ? 1.0f : mean_abs;
        out_tail[3] = (0.5f + dq) * 0.5f;  // consolidation_quality
    }
}

extern "C" void kernel_launch(void* const* d_in, const int* in_sizes, int n_in,
                              void* d_out, int out_size, void* d_ws, size_t ws_size,
                              hipStream_t stream) {
    const float* cur_w = (const float*)d_in[0];
    const float* w_chg = (const float*)d_in[1];
    const float* ur_w1 = (const float*)d_in[2];
    const float* ur_b1 = (const float*)d_in[3];
    const float* ur_w2 = (const float*)d_in[4];
    const float* ur_b2 = (const float*)d_in[5];
    const float* fg_w1 = (const float*)d_in[6];
    const float* fg_b1 = (const float*)d_in[7];
    const float* fg_w2 = (const float*)d_in[8];
    const float* fg_b2 = (const float*)d_in[9];

    int n = in_sizes[0];          // 16777216 (4096x4096)
    int n4 = n / 4;

    vfloat2* red_part = (vfloat2*)d_ws;
    float* abs_part = (float*)((char*)d_ws + NBLK * sizeof(vfloat2));
    float* wsf = (float*)((char*)d_ws + NBLK * sizeof(vfloat2) + NBLK * sizeof(float));

    float* out_w = (float*)d_out;
    float* out_tail = out_w + n;

    const int threads = 256;
    // 2048*256*8(unroll)*4(vec) == 16.7M exactly: the unrolled loop runs once, no tail.
    wc_reduce<<<NBLK, threads, 0, stream>>>((const vfloat4*)cur_w, (const vfloat4*)w_chg,
                                            red_part, n4);

    wc_scalars<<<1, 1024, 0, stream>>>(red_part, wsf, fg_w1, fg_b1, fg_w2, fg_b2, out_tail);

    wc_consolidate<<<NBLK, threads, 0, stream>>>((const vfloat4*)cur_w, (vfloat4*)out_w,
                                                 ur_w1, ur_b1, ur_w2, ur_b2, wsf, abs_part, n4);

    wc_finalize<<<1, 1024, 0, stream>>>(abs_part, out_tail, 1.0 / (double)n);
}

// Round 6
// 209.688 us; speedup vs baseline: 1.7686x; 1.0117x over previous
//
#include <hip/hip_runtime.h>
#include <math.h>

// True clang vector types (nontemporal builtins reject HIP_vector_type structs).
typedef float vfloat4 __attribute__((ext_vector_type(4)));
typedef float vfloat2 __attribute__((ext_vector_type(2)));

#define UNROLL 8
#define NBLK 2048

// ws layout (write-before-read each call; no init needed):
//   float   w_part[NBLK]   @0      : per-block ssq_w partials        (k1 -> k2)
//   vfloat2 cd_part[NBLK]  @8192   : per-block (sum_abs, ssq_dw)     (k3 -> k4)
//   float   wsf[2]         @24576  : final_strength, forgetting_strength (k2 -> k3)

// ---------------- k1: ssq over cur_w only (dw moved to k3) ----------------
__global__ __launch_bounds__(256, 4) void wc_reduce_w(const vfloat4* __restrict__ w,
                                                      float* __restrict__ w_part,
                                                      int n4) {
    int tid = blockIdx.x * blockDim.x + threadIdx.x;
    int stride = gridDim.x * blockDim.x;
    float s0 = 0.f, s1 = 0.f, s2 = 0.f, s3 = 0.f;
    int i = tid;
    for (; i + (UNROLL - 1) * stride < n4; i += UNROLL * stride) {
        vfloat4 a[UNROLL];
#pragma unroll
        for (int u = 0; u < UNROLL; u++) a[u] = w[i + u * stride];
#pragma unroll
        for (int u = 0; u < UNROLL; u++) {
            s0 = fmaf(a[u].x, a[u].x, s0);
            s1 = fmaf(a[u].y, a[u].y, s1);
            s2 = fmaf(a[u].z, a[u].z, s2);
            s3 = fmaf(a[u].w, a[u].w, s3);
        }
    }
    for (; i < n4; i += stride) {
        vfloat4 a = w[i];
        s0 = fmaf(a.x, a.x, s0); s1 = fmaf(a.y, a.y, s1);
        s2 = fmaf(a.z, a.z, s2); s3 = fmaf(a.w, a.w, s3);
    }
    float sw = (s0 + s1) + (s2 + s3);
    for (int off = 32; off > 0; off >>= 1) sw += __shfl_down(sw, off);
    __shared__ float ls[4];
    int wave = threadIdx.x >> 6;
    int lane = threadIdx.x & 63;
    if (lane == 0) ls[wave] = sw;
    __syncthreads();
    if (threadIdx.x == 0)
        w_part[blockIdx.x] = (ls[0] + ls[1]) + (ls[2] + ls[3]);  // contention-free
}

// ---------------- k2: fold partials -> fs, fg ----------------
__global__ __launch_bounds__(1024) void wc_scalars(const float* __restrict__ w_part,
                                                   float* __restrict__ wsf,
                                                   const float* __restrict__ fg_w1,
                                                   const float* __restrict__ fg_b1,
                                                   const float* __restrict__ fg_w2,
                                                   const float* __restrict__ fg_b2,
                                                   float* __restrict__ out_tail) {
    double sw = 0.0;
    for (int i = threadIdx.x; i < NBLK; i += 1024) sw += (double)w_part[i];
    for (int off = 32; off > 0; off >>= 1) sw += __shfl_down(sw, off);
    __shared__ double lsw[16];
    int wave = threadIdx.x >> 6;
    int lane = threadIdx.x & 63;
    if (lane == 0) lsw[wave] = sw;
    __syncthreads();
    if (threadIdx.x == 0) {
        double tw = 0.0;
        for (int k = 0; k < 16; k++) tw += lsw[k];
        float normw = sqrtf((float)tw);
        float fs = 1.0f / (1.0f + expf(-normw));
        fs = fminf(fmaxf(fs, 0.0f), 1.0f);
        const float tf = 0.01f, fr = 0.0001f;
        float acc = fg_b2[0];
        for (int j = 0; j < 8; j++) {
            float h = tf * fg_w1[2 * j + 0] + fr * fg_w1[2 * j + 1] + fg_b1[j];
            acc = fmaf(fmaxf(h, 0.0f), fg_w2[j], acc);
        }
        float fg = 1.0f / (1.0f + expf(-acc));
        wsf[0] = fs;
        wsf[1] = fg;
        out_tail[0] = fs;     // final_strength
        out_tail[2] = fg;     // forgetting_strength
        out_tail[4] = 0.5f;   // weight_stability
        out_tail[5] = 0.0f;   // memory_strength
    }
}

// ---- k3: consolidate + sum|new_w| + ssq_dw (dw read folded in here) ----
__global__ __launch_bounds__(256, 4) void wc_consolidate(const vfloat4* __restrict__ w,
                                                         const vfloat4* __restrict__ dw,
                                                         vfloat4* __restrict__ outw,
                                                         const float* __restrict__ ur_w1,
                                                         const float* __restrict__ ur_b1,
                                                         const float* __restrict__ ur_w2,
                                                         const float* __restrict__ ur_b2,
                                                         const float* __restrict__ wsf,
                                                         vfloat2* __restrict__ cd_part,
                                                         int n4) {
    float fs = wsf[0];
    float fg = wsf[1];
    float a0[16], hb[16], w2[16];
#pragma unroll
    for (int k = 0; k < 16; k++) {
        a0[k] = ur_w1[3 * k + 0];
        hb[k] = fmaf(fs, ur_w1[3 * k + 1], fmaf(fg, ur_w1[3 * k + 2], ur_b1[k]));
        w2[k] = ur_w2[k];
    }
    float b2 = ur_b2[0];

    int tid = blockIdx.x * blockDim.x + threadIdx.x;
    int stride = gridDim.x * blockDim.x;
    float sabs = 0.f;
    float sd0 = 0.f, sd1 = 0.f, sd2 = 0.f, sd3 = 0.f;
    int i = tid;
    for (; i + (UNROLL - 1) * stride < n4; i += UNROLL * stride) {
        vfloat4 v[UNROLL], d[UNROLL];
#pragma unroll
        for (int u = 0; u < UNROLL; u++) v[u] = w[i + u * stride];
#pragma unroll
        for (int u = 0; u < UNROLL; u++) d[u] = __builtin_nontemporal_load(&dw[i + u * stride]);
#pragma unroll
        for (int u = 0; u < UNROLL; u++) {
            sd0 = fmaf(d[u].x, d[u].x, sd0);
            sd1 = fmaf(d[u].y, d[u].y, sd1);
            sd2 = fmaf(d[u].z, d[u].z, sd2);
            sd3 = fmaf(d[u].w, d[u].w, sd3);
            vfloat4 o;
#pragma unroll
            for (int e = 0; e < 4; e++) {
                float x = v[u][e];
                float acc = b2;
#pragma unroll
                for (int k = 0; k < 16; k++) {
                    float h = fmaf(x, a0[k], hb[k]);
                    acc = fmaf(fmaxf(h, 0.0f), w2[k], acc);
                }
                float t = __expf(2.0f * acc);
                float th = fmaf(-2.0f, __builtin_amdgcn_rcpf(t + 1.0f), 1.0f);
                float nw = fmaf(0.001f, th, x);
                nw = fminf(fmaxf(nw, -10.0f), 10.0f);
                o[e] = nw;
                sabs += fabsf(nw);
            }
            __builtin_nontemporal_store(o, &outw[i + u * stride]);
        }
    }
    for (; i < n4; i += stride) {
        vfloat4 v = w[i];
        vfloat4 d = dw[i];
        sd0 = fmaf(d.x, d.x, sd0); sd1 = fmaf(d.y, d.y, sd1);
        sd2 = fmaf(d.z, d.z, sd2); sd3 = fmaf(d.w, d.w, sd3);
        vfloat4 o;
#pragma unroll
        for (int e = 0; e < 4; e++) {
            float x = v[e];
            float acc = b2;
#pragma unroll
            for (int k = 0; k < 16; k++) {
                float h = fmaf(x, a0[k], hb[k]);
                acc = fmaf(fmaxf(h, 0.0f), w2[k], acc);
            }
            float t = __expf(2.0f * acc);
            float th = fmaf(-2.0f, __builtin_amdgcn_rcpf(t + 1.0f), 1.0f);
            float nw = fmaf(0.001f, th, x);
            nw = fminf(fmaxf(nw, -10.0f), 10.0f);
            o[e] = nw;
            sabs += fabsf(nw);
        }
        outw[i] = o;
    }
    float sdw = (sd0 + sd1) + (sd2 + sd3);
    for (int off = 32; off > 0; off >>= 1) {
        sabs += __shfl_down(sabs, off);
        sdw  += __shfl_down(sdw, off);
    }
    __shared__ float lsa[4], lsd[4];
    int wave = threadIdx.x >> 6;
    int lane = threadIdx.x & 63;
    if (lane == 0) { lsa[wave] = sabs; lsd[wave] = sdw; }
    __syncthreads();
    if (threadIdx.x == 0) {
        vfloat2 p;
        p.x = (lsa[0] + lsa[1]) + (lsa[2] + lsa[3]);
        p.y = (lsd[0] + lsd[1]) + (lsd[2] + lsd[3]);
        cd_part[blockIdx.x] = p;   // no atomics
    }
}

// ---------------- k4: fold partials -> cm, quality ----------------
__global__ __launch_bounds__(1024) void wc_finalize(const vfloat2* __restrict__ cd_part,
                                                    float* __restrict__ out_tail,
                                                    double inv_n) {
    double sa = 0.0, sd = 0.0;
    for (int i = threadIdx.x; i < NBLK; i += 1024) {
        vfloat2 p = cd_part[i];
        sa += (double)p.x;
        sd += (double)p.y;
    }
    for (int off = 32; off > 0; off >>= 1) {
        sa += __shfl_down(sa, off);
        sd += __shfl_down(sd, off);
    }
    __shared__ double lsa[16], lsd[16];
    int wave = threadIdx.x >> 6;
    int lane = threadIdx.x & 63;
    if (lane == 0) { lsa[wave] = sa; lsd[wave] = sd; }
    __syncthreads();
    if (threadIdx.x == 0) {
        double ta = 0.0, td = 0.0;
        for (int k = 0; k < 16; k++) { ta += lsa[k]; td += lsd[k]; }
        out_tail[1] = sqrtf((float)td);          // change_magnitude
        float mean_abs = (float)(ta * inv_n);
        float dq = (mean_abs > 0.1f && mean_abs < 0.9f) ? 1.0f : mean_abs;
        out_tail[3] = (0.5f + dq) * 0.5f;        // consolidation_quality
    }
}

extern "C" void kernel_launch(void* const* d_in, const int* in_sizes, int n_in,
                              void* d_out, int out_size, void* d_ws, size_t ws_size,
                              hipStream_t stream) {
    const float* cur_w = (const float*)d_in[0];
    const float* w_chg = (const float*)d_in[1];
    const float* ur_w1 = (const float*)d_in[2];
    const float* ur_b1 = (const float*)d_in[3];
    const float* ur_w2 = (const float*)d_in[4];
    const float* ur_b2 = (const float*)d_in[5];
    const float* fg_w1 = (const float*)d_in[6];
    const float* fg_b1 = (const float*)d_in[7];
    const float* fg_w2 = (const float*)d_in[8];
    const float* fg_b2 = (const float*)d_in[9];

    int n = in_sizes[0];          // 16777216 (4096x4096)
    int n4 = n / 4;

    float* w_part = (float*)d_ws;
    vfloat2* cd_part = (vfloat2*)((char*)d_ws + 8192);
    float* wsf = (float*)((char*)d_ws + 24576);

    float* out_w = (float*)d_out;
    float* out_tail = out_w + n;

    const int threads = 256;
    // 2048*256*8(unroll)*4(vec) == 16.7M exactly: unrolled loop runs once, no tail.
    wc_reduce_w<<<NBLK, threads, 0, stream>>>((const vfloat4*)cur_w, w_part, n4);

    wc_scalars<<<1, 1024, 0, stream>>>(w_part, wsf, fg_w1, fg_b1, fg_w2, fg_b2, out_tail);

    wc_consolidate<<<NBLK, threads, 0, stream>>>((const vfloat4*)cur_w, (const vfloat4*)w_chg,
                                                 (vfloat4*)out_w, ur_w1, ur_b1, ur_w2, ur_b2,
                                                 wsf, cd_part, n4);

    wc_finalize<<<1, 1024, 0, stream>>>(cd_part, out_tail, 1.0 / (double)n);
}

// Round 7
// 201.782 us; speedup vs baseline: 1.8379x; 1.0392x over previous
//
#include <hip/hip_runtime.h>
#include <math.h>

// True clang vector types (nontemporal builtins + v_pk_* codegen need them).
typedef float vfloat4 __attribute__((ext_vector_type(4)));
typedef float vfloat2 __attribute__((ext_vector_type(2)));

#define UNROLL 8
#define NBLK 512       // 2 blocks/CU: persistent blocks, no relaunch bubbles
#define THREADS 256

// ws layout (write-before-read each call; no init needed):
//   float   w_part[NBLK]   @0     : per-block ssq_w partials        (k1 -> k2)
//   vfloat2 cd_part[NBLK]  @2048  : per-block (sum_abs, ssq_dw)     (k3 -> k4)
//   float   wsf[2]         @6144  : final_strength, forgetting_strength (k2 -> k3)

// ---------------- k1: ssq over cur_w ----------------
__global__ __launch_bounds__(256, 4) void wc_reduce_w(const vfloat4* __restrict__ w,
                                                      float* __restrict__ w_part,
                                                      int n4) {
    int tid = blockIdx.x * blockDim.x + threadIdx.x;
    int stride = gridDim.x * blockDim.x;     // 131072: 4 macro-iterations per thread
    float s0 = 0.f, s1 = 0.f, s2 = 0.f, s3 = 0.f;
    int i = tid;
    for (; i + (UNROLL - 1) * stride < n4; i += UNROLL * stride) {
        vfloat4 a[UNROLL];
#pragma unroll
        for (int u = 0; u < UNROLL; u++) a[u] = w[i + u * stride];
#pragma unroll
        for (int u = 0; u < UNROLL; u++) {
            s0 = fmaf(a[u].x, a[u].x, s0);
            s1 = fmaf(a[u].y, a[u].y, s1);
            s2 = fmaf(a[u].z, a[u].z, s2);
            s3 = fmaf(a[u].w, a[u].w, s3);
        }
    }
    for (; i < n4; i += stride) {
        vfloat4 a = w[i];
        s0 = fmaf(a.x, a.x, s0); s1 = fmaf(a.y, a.y, s1);
        s2 = fmaf(a.z, a.z, s2); s3 = fmaf(a.w, a.w, s3);
    }
    float sw = (s0 + s1) + (s2 + s3);
    for (int off = 32; off > 0; off >>= 1) sw += __shfl_down(sw, off);
    __shared__ float ls[4];
    int wave = threadIdx.x >> 6;
    int lane = threadIdx.x & 63;
    if (lane == 0) ls[wave] = sw;
    __syncthreads();
    if (threadIdx.x == 0)
        w_part[blockIdx.x] = (ls[0] + ls[1]) + (ls[2] + ls[3]);  // contention-free
}

// ---------------- k2: fold partials -> fs, fg ----------------
__global__ __launch_bounds__(512) void wc_scalars(const float* __restrict__ w_part,
                                                  float* __restrict__ wsf,
                                                  const float* __restrict__ fg_w1,
                                                  const float* __restrict__ fg_b1,
                                                  const float* __restrict__ fg_w2,
                                                  const float* __restrict__ fg_b2,
                                                  float* __restrict__ out_tail) {
    double sw = (double)w_part[threadIdx.x];   // 512 threads == NBLK
    for (int off = 32; off > 0; off >>= 1) sw += __shfl_down(sw, off);
    __shared__ double lsw[8];
    int wave = threadIdx.x >> 6;
    int lane = threadIdx.x & 63;
    if (lane == 0) lsw[wave] = sw;
    __syncthreads();
    if (threadIdx.x == 0) {
        double tw = 0.0;
        for (int k = 0; k < 8; k++) tw += lsw[k];
        float normw = sqrtf((float)tw);
        float fs = 1.0f / (1.0f + expf(-normw));
        fs = fminf(fmaxf(fs, 0.0f), 1.0f);
        const float tf = 0.01f, fr = 0.0001f;
        float acc = fg_b2[0];
        for (int j = 0; j < 8; j++) {
            float h = tf * fg_w1[2 * j + 0] + fr * fg_w1[2 * j + 1] + fg_b1[j];
            acc = fmaf(fmaxf(h, 0.0f), fg_w2[j], acc);
        }
        float fg = 1.0f / (1.0f + expf(-acc));
        wsf[0] = fs;
        wsf[1] = fg;
        out_tail[0] = fs;     // final_strength
        out_tail[2] = fg;     // forgetting_strength
        out_tail[4] = 0.5f;   // weight_stability
        out_tail[5] = 0.0f;   // memory_strength
    }
}

// ---- k3: consolidate + sum|new_w| + ssq_dw, packed-FP32 hinge loop ----
__global__ __launch_bounds__(256, 4) void wc_consolidate(const vfloat4* __restrict__ w,
                                                         const vfloat4* __restrict__ dw,
                                                         vfloat4* __restrict__ outw,
                                                         const float* __restrict__ ur_w1,
                                                         const float* __restrict__ ur_b1,
                                                         const float* __restrict__ ur_w2,
                                                         const float* __restrict__ ur_b2,
                                                         const float* __restrict__ wsf,
                                                         vfloat2* __restrict__ cd_part,
                                                         int n4) {
    float fs = wsf[0];
    float fg = wsf[1];
    float a0[16], hb[16], w2[16];
#pragma unroll
    for (int k = 0; k < 16; k++) {
        a0[k] = ur_w1[3 * k + 0];
        hb[k] = fmaf(fs, ur_w1[3 * k + 1], fmaf(fg, ur_w1[3 * k + 2], ur_b1[k]));
        w2[k] = ur_w2[k];
    }
    float b2 = ur_b2[0];

    int tid = blockIdx.x * blockDim.x + threadIdx.x;
    int stride = gridDim.x * blockDim.x;
    float sabs = 0.f;
    vfloat2 sdv01 = {0.f, 0.f}, sdv23 = {0.f, 0.f};
    int i = tid;
    for (; i + (UNROLL - 1) * stride < n4; i += UNROLL * stride) {
        vfloat4 v[UNROLL], d[UNROLL];
#pragma unroll
        for (int u = 0; u < UNROLL; u++) v[u] = w[i + u * stride];
#pragma unroll
        for (int u = 0; u < UNROLL; u++) d[u] = dw[i + u * stride];
#pragma unroll
        for (int u = 0; u < UNROLL; u++) {
            // ssq_dw, packed (2x v_pk_fma_f32)
            vfloat2 d01 = {d[u].x, d[u].y}, d23 = {d[u].z, d[u].w};
            sdv01 += d01 * d01;
            sdv23 += d23 * d23;
            // 16-hinge MLP on element pairs: v_pk_fma / v_pk_max.
            // Per-element math order identical to scalar version -> bitwise same.
            vfloat2 x01 = {v[u].x, v[u].y}, x23 = {v[u].z, v[u].w};
            vfloat2 acc01 = {b2, b2}, acc23 = {b2, b2};
#pragma unroll
            for (int k = 0; k < 16; k++) {
                vfloat2 h01 = x01 * a0[k] + hb[k];   // contracts to pk_fma
                vfloat2 h23 = x23 * a0[k] + hb[k];
                h01 = __builtin_elementwise_max(h01, (vfloat2)0.0f);
                h23 = __builtin_elementwise_max(h23, (vfloat2)0.0f);
                acc01 += h01 * w2[k];
                acc23 += h23 * w2[k];
            }
            float accs[4] = {acc01.x, acc01.y, acc23.x, acc23.y};
            float xs[4] = {v[u].x, v[u].y, v[u].z, v[u].w};
            vfloat4 o;
#pragma unroll
            for (int e = 0; e < 4; e++) {
                float t = __expf(2.0f * accs[e]);
                float th = fmaf(-2.0f, __builtin_amdgcn_rcpf(t + 1.0f), 1.0f);
                float nw = fmaf(0.001f, th, xs[e]);
                nw = fminf(fmaxf(nw, -10.0f), 10.0f);
                o[e] = nw;
                sabs += fabsf(nw);
            }
            __builtin_nontemporal_store(o, &outw[i + u * stride]);
        }
    }
    for (; i < n4; i += stride) {     // generic tail (not executed at n=16.7M)
        vfloat4 v = w[i];
        vfloat4 d = dw[i];
        vfloat2 d01 = {d.x, d.y}, d23 = {d.z, d.w};
        sdv01 += d01 * d01;
        sdv23 += d23 * d23;
        vfloat4 o;
#pragma unroll
        for (int e = 0; e < 4; e++) {
            float x = v[e];
            float acc = b2;
#pragma unroll
            for (int k = 0; k < 16; k++) {
                float h = fmaf(x, a0[k], hb[k]);
                acc = fmaf(fmaxf(h, 0.0f), w2[k], acc);
            }
            float t = __expf(2.0f * acc);
            float th = fmaf(-2.0f, __builtin_amdgcn_rcpf(t + 1.0f), 1.0f);
            float nw = fmaf(0.001f, th, x);
            nw = fminf(fmaxf(nw, -10.0f), 10.0f);
            o[e] = nw;
            sabs += fabsf(nw);
        }
        outw[i] = o;
    }
    float sdw = (sdv01.x + sdv01.y) + (sdv23.x + sdv23.y);
    for (int off = 32; off > 0; off >>= 1) {
        sabs += __shfl_down(sabs, off);
        sdw  += __shfl_down(sdw, off);
    }
    __shared__ float lsa[4], lsd[4];
    int wave = threadIdx.x >> 6;
    int lane = threadIdx.x & 63;
    if (lane == 0) { lsa[wave] = sabs; lsd[wave] = sdw; }
    __syncthreads();
    if (threadIdx.x == 0) {
        vfloat2 p;
        p.x = (lsa[0] + lsa[1]) + (lsa[2] + lsa[3]);
        p.y = (lsd[0] + lsd[1]) + (lsd[2] + lsd[3]);
        cd_part[blockIdx.x] = p;   // no atomics
    }
}

// ---------------- k4: fold partials -> cm, quality ----------------
__global__ __launch_bounds__(512) void wc_finalize(const vfloat2* __restrict__ cd_part,
                                                   float* __restrict__ out_tail,
                                                   double inv_n) {
    vfloat2 p = cd_part[threadIdx.x];    // 512 threads == NBLK
    double sa = (double)p.x, sd = (double)p.y;
    for (int off = 32; off > 0; off >>= 1) {
        sa += __shfl_down(sa, off);
        sd += __shfl_down(sd, off);
    }
    __shared__ double lsa[8], lsd[8];
    int wave = threadIdx.x >> 6;
    int lane = threadIdx.x & 63;
    if (lane == 0) { lsa[wave] = sa; lsd[wave] = sd; }
    __syncthreads();
    if (threadIdx.x == 0) {
        double ta = 0.0, td = 0.0;
        for (int k = 0; k < 8; k++) { ta += lsa[k]; td += lsd[k]; }
        out_tail[1] = sqrtf((float)td);          // change_magnitude
        float mean_abs = (float)(ta * inv_n);
        float dq = (mean_abs > 0.1f && mean_abs < 0.9f) ? 1.0f : mean_abs;
        out_tail[3] = (0.5f + dq) * 0.5f;        // consolidation_quality
    }
}

extern "C" void kernel_launch(void* const* d_in, const int* in_sizes, int n_in,
                              void* d_out, int out_size, void* d_ws, size_t ws_size,
                              hipStream_t stream) {
    const float* cur_w = (const float*)d_in[0];
    const float* w_chg = (const float*)d_in[1];
    const float* ur_w1 = (const float*)d_in[2];
    const float* ur_b1 = (const float*)d_in[3];
    const float* ur_w2 = (const float*)d_in[4];
    const float* ur_b2 = (const float*)d_in[5];
    const float* fg_w1 = (const float*)d_in[6];
    const float* fg_b1 = (const float*)d_in[7];
    const float* fg_w2 = (const float*)d_in[8];
    const float* fg_b2 = (const float*)d_in[9];

    int n = in_sizes[0];          // 16777216 (4096x4096)
    int n4 = n / 4;

    float* w_part = (float*)d_ws;
    vfloat2* cd_part = (vfloat2*)((char*)d_ws + 2048);
    float* wsf = (float*)((char*)d_ws + 6144);

    float* out_w = (float*)d_out;
    float* out_tail = out_w + n;

    // 512 blocks * 256 thr * 8 unroll * 4 floats * 4 macro-iters == 16.7M exactly.
    wc_reduce_w<<<NBLK, THREADS, 0, stream>>>((const vfloat4*)cur_w, w_part, n4);

    wc_scalars<<<1, 512, 0, stream>>>(w_part, wsf, fg_w1, fg_b1, fg_w2, fg_b2, out_tail);

    wc_consolidate<<<NBLK, THREADS, 0, stream>>>((const vfloat4*)cur_w, (const vfloat4*)w_chg,
                                                 (vfloat4*)out_w, ur_w1, ur_b1, ur_w2, ur_b2,
                                                 wsf, cd_part, n4);

    wc_finalize<<<1, 512, 0, stream>>>(cd_part, out_tail, 1.0 / (double)n);
}

// Round 8
// 201.433 us; speedup vs baseline: 1.8411x; 1.0017x over previous
//
#include <hip/hip_runtime.h>
#include <math.h>

// True clang vector types (v_pk_* codegen needs them).
typedef float vfloat4 __attribute__((ext_vector_type(4)));
typedef float vfloat2 __attribute__((ext_vector_type(2)));

#define UNROLL 8
#define NBLK 2048      // R6's best shape: one UNROLL-8 burst per block, no macro-loop
#define THREADS 256

// ws layout (write-before-read each call; no init needed):
//   float   w_part[NBLK]   @0      : per-block ssq_w partials        (k1 -> k2)
//   vfloat2 cd_part[NBLK]  @8192   : per-block (sum_abs, ssq_dw)     (k3 -> k4)
//   float   wsf[2]         @24576  : final_strength, forgetting_strength (k2 -> k3)

// ---------------- k1: ssq over cur_w ----------------
__global__ __launch_bounds__(256) void wc_reduce_w(const vfloat4* __restrict__ w,
                                                   float* __restrict__ w_part,
                                                   int n4) {
    int tid = blockIdx.x * blockDim.x + threadIdx.x;
    int stride = gridDim.x * blockDim.x;
    float s0 = 0.f, s1 = 0.f, s2 = 0.f, s3 = 0.f;
    int i = tid;
    for (; i + (UNROLL - 1) * stride < n4; i += UNROLL * stride) {
        vfloat4 a[UNROLL];
#pragma unroll
        for (int u = 0; u < UNROLL; u++) a[u] = w[i + u * stride];
#pragma unroll
        for (int u = 0; u < UNROLL; u++) {
            s0 = fmaf(a[u].x, a[u].x, s0);
            s1 = fmaf(a[u].y, a[u].y, s1);
            s2 = fmaf(a[u].z, a[u].z, s2);
            s3 = fmaf(a[u].w, a[u].w, s3);
        }
    }
    for (; i < n4; i += stride) {
        vfloat4 a = w[i];
        s0 = fmaf(a.x, a.x, s0); s1 = fmaf(a.y, a.y, s1);
        s2 = fmaf(a.z, a.z, s2); s3 = fmaf(a.w, a.w, s3);
    }
    float sw = (s0 + s1) + (s2 + s3);
    for (int off = 32; off > 0; off >>= 1) sw += __shfl_down(sw, off);
    __shared__ float ls[4];
    int wave = threadIdx.x >> 6;
    int lane = threadIdx.x & 63;
    if (lane == 0) ls[wave] = sw;
    __syncthreads();
    if (threadIdx.x == 0)
        w_part[blockIdx.x] = (ls[0] + ls[1]) + (ls[2] + ls[3]);  // contention-free
}

// ---------------- k2: fold partials -> fs, fg ----------------
__global__ __launch_bounds__(1024) void wc_scalars(const float* __restrict__ w_part,
                                                   float* __restrict__ wsf,
                                                   const float* __restrict__ fg_w1,
                                                   const float* __restrict__ fg_b1,
                                                   const float* __restrict__ fg_w2,
                                                   const float* __restrict__ fg_b2,
                                                   float* __restrict__ out_tail) {
    double sw = 0.0;
    for (int i = threadIdx.x; i < NBLK; i += 1024) sw += (double)w_part[i];
    for (int off = 32; off > 0; off >>= 1) sw += __shfl_down(sw, off);
    __shared__ double lsw[16];
    int wave = threadIdx.x >> 6;
    int lane = threadIdx.x & 63;
    if (lane == 0) lsw[wave] = sw;
    __syncthreads();
    if (threadIdx.x == 0) {
        double tw = 0.0;
        for (int k = 0; k < 16; k++) tw += lsw[k];
        float normw = sqrtf((float)tw);
        float fs = 1.0f / (1.0f + expf(-normw));
        fs = fminf(fmaxf(fs, 0.0f), 1.0f);
        const float tf = 0.01f, fr = 0.0001f;
        float acc = fg_b2[0];
        for (int j = 0; j < 8; j++) {
            float h = tf * fg_w1[2 * j + 0] + fr * fg_w1[2 * j + 1] + fg_b1[j];
            acc = fmaf(fmaxf(h, 0.0f), fg_w2[j], acc);
        }
        float fg = 1.0f / (1.0f + expf(-acc));
        wsf[0] = fs;
        wsf[1] = fg;
        out_tail[0] = fs;     // final_strength
        out_tail[2] = fg;     // forgetting_strength
        out_tail[4] = 0.5f;   // weight_stability
        out_tail[5] = 0.0f;   // memory_strength
    }
}

// ---- k3: consolidate + sum|new_w| + ssq_dw, packed-FP32, plain stores ----
__global__ __launch_bounds__(256) void wc_consolidate(const vfloat4* __restrict__ w,
                                                      const vfloat4* __restrict__ dw,
                                                      vfloat4* __restrict__ outw,
                                                      const float* __restrict__ ur_w1,
                                                      const float* __restrict__ ur_b1,
                                                      const float* __restrict__ ur_w2,
                                                      const float* __restrict__ ur_b2,
                                                      const float* __restrict__ wsf,
                                                      vfloat2* __restrict__ cd_part,
                                                      int n4) {
    float fs = wsf[0];
    float fg = wsf[1];
    float a0[16], hb[16], w2[16];
#pragma unroll
    for (int k = 0; k < 16; k++) {
        a0[k] = ur_w1[3 * k + 0];
        hb[k] = fmaf(fs, ur_w1[3 * k + 1], fmaf(fg, ur_w1[3 * k + 2], ur_b1[k]));
        w2[k] = ur_w2[k];
    }
    float b2 = ur_b2[0];

    int tid = blockIdx.x * blockDim.x + threadIdx.x;
    int stride = gridDim.x * blockDim.x;
    float sabs = 0.f;
    vfloat2 sdv01 = {0.f, 0.f}, sdv23 = {0.f, 0.f};
    int i = tid;
    for (; i + (UNROLL - 1) * stride < n4; i += UNROLL * stride) {
        vfloat4 v[UNROLL], d[UNROLL];
#pragma unroll
        for (int u = 0; u < UNROLL; u++) v[u] = w[i + u * stride];
#pragma unroll
        for (int u = 0; u < UNROLL; u++) d[u] = dw[i + u * stride];
#pragma unroll
        for (int u = 0; u < UNROLL; u++) {
            // ssq_dw, packed (v_pk_fma_f32)
            vfloat2 d01 = {d[u].x, d[u].y}, d23 = {d[u].z, d[u].w};
            sdv01 += d01 * d01;
            sdv23 += d23 * d23;
            // 16-hinge MLP on element pairs: v_pk_fma / v_pk_max.
            vfloat2 x01 = {v[u].x, v[u].y}, x23 = {v[u].z, v[u].w};
            vfloat2 acc01 = {b2, b2}, acc23 = {b2, b2};
#pragma unroll
            for (int k = 0; k < 16; k++) {
                vfloat2 h01 = x01 * a0[k] + hb[k];
                vfloat2 h23 = x23 * a0[k] + hb[k];
                h01 = __builtin_elementwise_max(h01, (vfloat2)0.0f);
                h23 = __builtin_elementwise_max(h23, (vfloat2)0.0f);
                acc01 += h01 * w2[k];
                acc23 += h23 * w2[k];
            }
            float accs[4] = {acc01.x, acc01.y, acc23.x, acc23.y};
            float xs[4] = {v[u].x, v[u].y, v[u].z, v[u].w};
            vfloat4 o;
#pragma unroll
            for (int e = 0; e < 4; e++) {
                float t = __expf(2.0f * accs[e]);
                float th = fmaf(-2.0f, __builtin_amdgcn_rcpf(t + 1.0f), 1.0f);
                float nw = fmaf(0.001f, th, xs[e]);
                nw = fminf(fmaxf(nw, -10.0f), 10.0f);
                o[e] = nw;
                sabs += fabsf(nw);
            }
            outw[i + u * stride] = o;    // plain cacheable store: let L2/L3 defer
        }
    }
    for (; i < n4; i += stride) {     // generic tail (not executed at n=16.7M)
        vfloat4 v = w[i];
        vfloat4 d = dw[i];
        vfloat2 d01 = {d.x, d.y}, d23 = {d.z, d.w};
        sdv01 += d01 * d01;
        sdv23 += d23 * d23;
        vfloat4 o;
#pragma unroll
        for (int e = 0; e < 4; e++) {
            float x = v[e];
            float acc = b2;
#pragma unroll
            for (int k = 0; k < 16; k++) {
                float h = fmaf(x, a0[k], hb[k]);
                acc = fmaf(fmaxf(h, 0.0f), w2[k], acc);
            }
            float t = __expf(2.0f * acc);
            float th = fmaf(-2.0f, __builtin_amdgcn_rcpf(t + 1.0f), 1.0f);
            float nw = fmaf(0.001f, th, x);
            nw = fminf(fmaxf(nw, -10.0f), 10.0f);
            o[e] = nw;
            sabs += fabsf(nw);
        }
        outw[i] = o;
    }
    float sdw = (sdv01.x + sdv01.y) + (sdv23.x + sdv23.y);
    for (int off = 32; off > 0; off >>= 1) {
        sabs += __shfl_down(sabs, off);
        sdw  += __shfl_down(sdw, off);
    }
    __shared__ float lsa[4], lsd[4];
    int wave = threadIdx.x >> 6;
    int lane = threadIdx.x & 63;
    if (lane == 0) { lsa[wave] = sabs; lsd[wave] = sdw; }
    __syncthreads();
    if (threadIdx.x == 0) {
        vfloat2 p;
        p.x = (lsa[0] + lsa[1]) + (lsa[2] + lsa[3]);
        p.y = (lsd[0] + lsd[1]) + (lsd[2] + lsd[3]);
        cd_part[blockIdx.x] = p;   // no atomics
    }
}

// ---------------- k4: fold partials -> cm, quality ----------------
__global__ __launch_bounds__(1024) void wc_finalize(const vfloat2* __restrict__ cd_part,
                                                    float* __restrict__ out_tail,
                                                    double inv_n) {
    double sa = 0.0, sd = 0.0;
    for (int i = threadIdx.x; i < NBLK; i += 1024) {
        vfloat2 p = cd_part[i];
        sa += (double)p.x;
        sd += (double)p.y;
    }
    for (int off = 32; off > 0; off >>= 1) {
        sa += __shfl_down(sa, off);
        sd += __shfl_down(sd, off);
    }
    __shared__ double lsa[16], lsd[16];
    int wave = threadIdx.x >> 6;
    int lane = threadIdx.x & 63;
    if (lane == 0) { lsa[wave] = sa; lsd[wave] = sd; }
    __syncthreads();
    if (threadIdx.x == 0) {
        double ta = 0.0, td = 0.0;
        for (int k = 0; k < 16; k++) { ta += lsa[k]; td += lsd[k]; }
        out_tail[1] = sqrtf((float)td);          // change_magnitude
        float mean_abs = (float)(ta * inv_n);
        float dq = (mean_abs > 0.1f && mean_abs < 0.9f) ? 1.0f : mean_abs;
        out_tail[3] = (0.5f + dq) * 0.5f;        // consolidation_quality
    }
}

extern "C" void kernel_launch(void* const* d_in, const int* in_sizes, int n_in,
                              void* d_out, int out_size, void* d_ws, size_t ws_size,
                              hipStream_t stream) {
    const float* cur_w = (const float*)d_in[0];
    const float* w_chg = (const float*)d_in[1];
    const float* ur_w1 = (const float*)d_in[2];
    const float* ur_b1 = (const float*)d_in[3];
    const float* ur_w2 = (const float*)d_in[4];
    const float* ur_b2 = (const float*)d_in[5];
    const float* fg_w1 = (const float*)d_in[6];
    const float* fg_b1 = (const float*)d_in[7];
    const float* fg_w2 = (const float*)d_in[8];
    const float* fg_b2 = (const float*)d_in[9];

    int n = in_sizes[0];          // 16777216 (4096x4096)
    int n4 = n / 4;

    float* w_part = (float*)d_ws;
    vfloat2* cd_part = (vfloat2*)((char*)d_ws + 8192);
    float* wsf = (float*)((char*)d_ws + 24576);

    float* out_w = (float*)d_out;
    float* out_tail = out_w + n;

    // 2048 blocks * 256 thr * 8 unroll * 4 floats == 16.7M exactly: one burst, no tail.
    wc_reduce_w<<<NBLK, THREADS, 0, stream>>>((const vfloat4*)cur_w, w_part, n4);

    wc_scalars<<<1, 1024, 0, stream>>>(w_part, wsf, fg_w1, fg_b1, fg_w2, fg_b2, out_tail);

    wc_consolidate<<<NBLK, THREADS, 0, stream>>>((const vfloat4*)cur_w, (const vfloat4*)w_chg,
                                                 (vfloat4*)out_w, ur_w1, ur_b1, ur_w2, ur_b2,
                                                 wsf, cd_part, n4);

    wc_finalize<<<1, 1024, 0, stream>>>(cd_part, out_tail, 1.0 / (double)n);
}